// Round 1
// baseline (5741.019 us; speedup 1.0000x reference)
//
#include <hip/hip_runtime.h>

#define NN 100000
#define NE 1600000

// ---------------------------------------------------------------------------
// Weight folding:
//   M[128][128]: cols 0-63  = A = wn @ wm1[0:64,:]   (node -> message preact)
//                cols 64-127= wu1[0:128,:]           (node -> update preact)
//   B[32][64]  : we @ wm1[64:128,:]                  (edge -> message preact)
//   c[64]      : bm1 + bn@wm1[0:64,:] + be@wm1[64:128,:]
// ---------------------------------------------------------------------------
__global__ __launch_bounds__(256) void k_fold(
    const float* __restrict__ wn, const float* __restrict__ bn,
    const float* __restrict__ we, const float* __restrict__ be,
    const float* __restrict__ wm1, const float* __restrict__ bm1,
    const float* __restrict__ wu1,
    float* __restrict__ M, float* __restrict__ B, float* __restrict__ c) {
  int t = blockIdx.x * 256 + threadIdx.x;
  if (t < 128 * 128) {
    int k = t >> 7, j = t & 127;
    float acc;
    if (j < 64) {
      acc = 0.f;
      for (int h = 0; h < 64; ++h) acc += wn[k * 64 + h] * wm1[h * 64 + j];
    } else {
      acc = wu1[k * 64 + (j - 64)];
    }
    M[t] = acc;
  } else if (t < 128 * 128 + 32 * 64) {
    int u = t - 128 * 128;
    int k = u >> 6, j = u & 63;
    float acc = 0.f;
    for (int h = 0; h < 64; ++h) acc += we[k * 64 + h] * wm1[(64 + h) * 64 + j];
    B[u] = acc;
  } else if (t < 128 * 128 + 32 * 64 + 64) {
    int j = t - (128 * 128 + 32 * 64);
    float acc = bm1[j];
    for (int h = 0; h < 64; ++h)
      acc += bn[h] * wm1[h * 64 + j] + be[h] * wm1[(64 + h) * 64 + j];
    c[j] = acc;
  }
}

// ---------------------------------------------------------------------------
// PR[n][0:128] = nf[n][0:128] @ M.  Lane-per-node; M accessed with uniform
// indices -> scalar loads (s_load), fmacs are v_fmac v,s,v at full rate.
// ---------------------------------------------------------------------------
__global__ __launch_bounds__(256) void k_node(
    const float* __restrict__ nf, const float* __restrict__ M,
    float* __restrict__ PR) {
  int n = blockIdx.x * 256 + threadIdx.x;
  if (n >= NN) return;
  const float* __restrict__ row = &nf[(size_t)n * 128];
#pragma unroll 1
  for (int jc = 0; jc < 128; jc += 32) {
    float q[32];
#pragma unroll
    for (int jj = 0; jj < 32; ++jj) q[jj] = 0.f;
#pragma unroll 4
    for (int k = 0; k < 128; k += 4) {
      float4 r4 = *(const float4*)&row[k];
#pragma unroll
      for (int jj = 0; jj < 32; ++jj) q[jj] += r4.x * M[(k + 0) * 128 + jc + jj];
#pragma unroll
      for (int jj = 0; jj < 32; ++jj) q[jj] += r4.y * M[(k + 1) * 128 + jc + jj];
#pragma unroll
      for (int jj = 0; jj < 32; ++jj) q[jj] += r4.z * M[(k + 2) * 128 + jc + jj];
#pragma unroll
      for (int jj = 0; jj < 32; ++jj) q[jj] += r4.w * M[(k + 3) * 128 + jc + jj];
    }
#pragma unroll
    for (int jj = 0; jj < 32; jj += 4)
      *(float4*)&PR[(size_t)n * 128 + jc + jj] = make_float4(q[jj], q[jj + 1], q[jj + 2], q[jj + 3]);
  }
}

// ---------------------------------------------------------------------------
// Per edge e (one lane per edge):
//   q[j]  = c[j] + sum_k ef[e][k]*B[k][j]
//   h[j]  = relu(PR[src][j] + q[j])
//   m[o]  = bm2[o] + sum_j h[j]*wm2[j][o]
//   atomicAdd(agg[dst][o], m[o])
// Weights (B, c, wm2, bm2) all uniform-indexed -> scalar loads.
// ---------------------------------------------------------------------------
__global__ __launch_bounds__(256) void k_edge(
    const int* __restrict__ idx, const float* __restrict__ ef,
    const float* __restrict__ B, const float* __restrict__ c,
    const float* __restrict__ wm2, const float* __restrict__ bm2,
    const float* __restrict__ PR, float* __restrict__ agg) {
  int e = blockIdx.x * 256 + threadIdx.x;
  if (e >= NE) return;
  int src = idx[e];
  int dst = idx[NE + e];

  float efr[32];
#pragma unroll
  for (int k = 0; k < 32; k += 4)
    *(float4*)&efr[k] = *(const float4*)&ef[(size_t)e * 32 + k];

  float m[64];
#pragma unroll
  for (int o = 0; o < 64; ++o) m[o] = bm2[o];

  const float* __restrict__ prs = &PR[(size_t)src * 128];

#pragma unroll 1
  for (int jc = 0; jc < 64; jc += 16) {
    float q[16];
#pragma unroll
    for (int jj = 0; jj < 16; ++jj) q[jj] = c[jc + jj];
#pragma unroll
    for (int k = 0; k < 32; ++k) {
      float ev = efr[k];
#pragma unroll
      for (int jj = 0; jj < 16; ++jj) q[jj] += ev * B[k * 64 + jc + jj];
    }
#pragma unroll
    for (int jj = 0; jj < 16; ++jj) {
      float h = prs[jc + jj] + q[jj];
      h = fmaxf(h, 0.f);
#pragma unroll
      for (int o = 0; o < 64; ++o) m[o] += h * wm2[(jc + jj) * 64 + o];
    }
  }

  float* __restrict__ ap = &agg[(size_t)dst * 64];
#pragma unroll
  for (int o = 0; o < 64; ++o) atomicAdd(&ap[o], m[o]);
}

// ---------------------------------------------------------------------------
// Per node n (one lane per node):
//   h[j]  = relu(PR[n][64+j] + sum_k agg[n][k]*wu1[128+k][j] + bu1[j])
//   out[o]= bu2[o] + sum_j h[j]*wu2[j][o]
// ---------------------------------------------------------------------------
__global__ __launch_bounds__(256) void k_update(
    const float* __restrict__ agg, const float* __restrict__ PR,
    const float* __restrict__ wu1, const float* __restrict__ bu1,
    const float* __restrict__ wu2, const float* __restrict__ bu2,
    float* __restrict__ out) {
  int n = blockIdx.x * 256 + threadIdx.x;
  if (n >= NN) return;

  float ar[64];
#pragma unroll
  for (int k = 0; k < 64; k += 4)
    *(float4*)&ar[k] = *(const float4*)&agg[(size_t)n * 64 + k];

  float acc[64];
#pragma unroll
  for (int o = 0; o < 64; ++o) acc[o] = bu2[o];

  const float* __restrict__ prs = &PR[(size_t)n * 128 + 64];

#pragma unroll 1
  for (int jc = 0; jc < 64; jc += 16) {
    float q[16];
#pragma unroll
    for (int jj = 0; jj < 16; ++jj) q[jj] = bu1[jc + jj];
#pragma unroll
    for (int k = 0; k < 64; ++k) {
      float av = ar[k];
#pragma unroll
      for (int jj = 0; jj < 16; ++jj) q[jj] += av * wu1[(128 + k) * 64 + jc + jj];
    }
#pragma unroll
    for (int jj = 0; jj < 16; ++jj) {
      float h = prs[jc + jj] + q[jj];
      h = fmaxf(h, 0.f);
#pragma unroll
      for (int o = 0; o < 64; ++o) acc[o] += h * wu2[(jc + jj) * 64 + o];
    }
  }

#pragma unroll
  for (int o = 0; o < 64; o += 4)
    *(float4*)&out[(size_t)n * 64 + o] = make_float4(acc[o], acc[o + 1], acc[o + 2], acc[o + 3]);
}

extern "C" void kernel_launch(void* const* d_in, const int* in_sizes, int n_in,
                              void* d_out, int out_size, void* d_ws, size_t ws_size,
                              hipStream_t stream) {
  const float* nf  = (const float*)d_in[0];
  const int*   idx = (const int*)d_in[1];
  const float* ef  = (const float*)d_in[2];
  const float* wn  = (const float*)d_in[3];
  const float* bn  = (const float*)d_in[4];
  const float* we  = (const float*)d_in[5];
  const float* be  = (const float*)d_in[6];
  const float* wm1 = (const float*)d_in[7];
  const float* bm1 = (const float*)d_in[8];
  const float* wm2 = (const float*)d_in[9];
  const float* bm2 = (const float*)d_in[10];
  const float* wu1 = (const float*)d_in[11];
  const float* bu1 = (const float*)d_in[12];
  const float* wu2 = (const float*)d_in[13];
  const float* bu2 = (const float*)d_in[14];
  float* out = (float*)d_out;

  // Workspace layout (floats)
  float* M   = (float*)d_ws;            // 128*128 = 16384
  float* B   = M + 16384;               // 32*64   = 2048
  float* c   = B + 2048;                // 64
  float* PR  = c + 64;                  // NN*128  = 12,800,000
  float* agg = PR + (size_t)NN * 128;   // NN*64   = 6,400,000

  // 1. fold weights
  k_fold<<<(16384 + 2048 + 64 + 255) / 256, 256, 0, stream>>>(
      wn, bn, we, be, wm1, bm1, wu1, M, B, c);

  // 2. per-node precompute PR = nf @ M
  k_node<<<(NN + 255) / 256, 256, 0, stream>>>(nf, M, PR);

  // 3. zero aggregation buffer
  hipMemsetAsync(agg, 0, (size_t)NN * 64 * sizeof(float), stream);

  // 4. per-edge message + scatter
  k_edge<<<NE / 256, 256, 0, stream>>>(idx, ef, B, c, wm2, bm2, PR, agg);

  // 5. per-node update MLP
  k_update<<<(NN + 255) / 256, 256, 0, stream>>>(
      agg, PR, wu1, bu1, wu2, bu2, out);
}

// Round 2
// 1072.418 us; speedup vs baseline: 5.3533x; 5.3533x over previous
//
#include <hip/hip_runtime.h>

#define NN 100000
#define NE 1600000

// ---------------------------------------------------------------------------
// Workspace layout in 4-byte units
// ---------------------------------------------------------------------------
#define OFF_M    0                        // 128*128 folded [A | wu1_top]
#define OFF_B    (OFF_M + 16384)          // 32*64   we @ wm1_bot
#define OFF_C    (OFF_B + 2048)           // 64      folded bias
#define OFF_PRA  (OFF_C + 64)             // NN*64   nf @ A
#define OFF_PRU  (OFF_PRA + NN * 64)      // NN*64   nf @ wu1_top
#define OFF_H    (OFF_PRU + NN * 64)      // NN*64   Sigma relu(h)  (or agg in fallback)
#define OFF_HIST (OFF_H + NN * 64)        // NN ints
#define OFF_CUR  (OFF_HIST + NN)          // NN ints
#define OFF_STRT (OFF_CUR + NN)           // NN+1 ints
#define OFF_ES   (OFF_STRT + NN + 4)      // NE ints: edge id sorted by dst
#define OFF_SRCS (OFF_ES + NE)            // NE ints: src sorted by dst
#define WS_UNITS (OFF_SRCS + NE)

// ---------------------------------------------------------------------------
// Weight folding (unchanged math from round 1):
//   M[128][128]: cols 0-63 = wn@wm1_top ; cols 64-127 = wu1[0:128,:]
//   B[32][64]   = we @ wm1_bot
//   c[64]       = bm1 + bn@wm1_top + be@wm1_bot
// ---------------------------------------------------------------------------
__global__ __launch_bounds__(256) void k_fold(
    const float* __restrict__ wn, const float* __restrict__ bn,
    const float* __restrict__ we, const float* __restrict__ be,
    const float* __restrict__ wm1, const float* __restrict__ bm1,
    const float* __restrict__ wu1,
    float* __restrict__ M, float* __restrict__ B, float* __restrict__ c) {
  int t = blockIdx.x * 256 + threadIdx.x;
  if (t < 128 * 128) {
    int k = t >> 7, j = t & 127;
    float acc;
    if (j < 64) {
      acc = 0.f;
      for (int h = 0; h < 64; ++h) acc += wn[k * 64 + h] * wm1[h * 64 + j];
    } else {
      acc = wu1[k * 64 + (j - 64)];
    }
    M[t] = acc;
  } else if (t < 128 * 128 + 32 * 64) {
    int u = t - 128 * 128;
    int k = u >> 6, j = u & 63;
    float acc = 0.f;
    for (int h = 0; h < 64; ++h) acc += we[k * 64 + h] * wm1[(64 + h) * 64 + j];
    B[u] = acc;
  } else if (t < 128 * 128 + 32 * 64 + 64) {
    int j = t - (128 * 128 + 32 * 64);
    float acc = bm1[j];
    for (int h = 0; h < 64; ++h)
      acc += bn[h] * wm1[h * 64 + j] + be[h] * wm1[(64 + h) * 64 + j];
    c[j] = acc;
  }
}

// ---------------------------------------------------------------------------
// PRA[n][j] = (nf[n] @ A)[j], PRU[n][j] = (nf[n] @ wu1_top)[j]
// ---------------------------------------------------------------------------
__global__ __launch_bounds__(256) void k_node(
    const float* __restrict__ nf, const float* __restrict__ M,
    float* __restrict__ PRA, float* __restrict__ PRU) {
  int n = blockIdx.x * 256 + threadIdx.x;
  if (n >= NN) return;
  const float* __restrict__ row = &nf[(size_t)n * 128];
#pragma unroll 1
  for (int jc = 0; jc < 128; jc += 32) {
    float q[32];
#pragma unroll
    for (int jj = 0; jj < 32; ++jj) q[jj] = 0.f;
#pragma unroll 4
    for (int k = 0; k < 128; k += 4) {
      float4 r4 = *(const float4*)&row[k];
#pragma unroll
      for (int jj = 0; jj < 32; ++jj) q[jj] += r4.x * M[(k + 0) * 128 + jc + jj];
#pragma unroll
      for (int jj = 0; jj < 32; ++jj) q[jj] += r4.y * M[(k + 1) * 128 + jc + jj];
#pragma unroll
      for (int jj = 0; jj < 32; ++jj) q[jj] += r4.z * M[(k + 2) * 128 + jc + jj];
#pragma unroll
      for (int jj = 0; jj < 32; ++jj) q[jj] += r4.w * M[(k + 3) * 128 + jc + jj];
    }
    float* dstp = (jc < 64) ? &PRA[(size_t)n * 64 + jc] : &PRU[(size_t)n * 64 + (jc - 64)];
#pragma unroll
    for (int jj = 0; jj < 32; jj += 4)
      *(float4*)&dstp[jj] = make_float4(q[jj], q[jj + 1], q[jj + 2], q[jj + 3]);
  }
}

// ---------------------------------------------------------------------------
// Counting-sort by dst: histogram -> scan -> scatter
// ---------------------------------------------------------------------------
__global__ __launch_bounds__(256) void k_hist(const int* __restrict__ idx,
                                              int* __restrict__ hist) {
  int e = blockIdx.x * 256 + threadIdx.x;
  if (e < NE) atomicAdd(&hist[idx[NE + e]], 1);
}

__global__ __launch_bounds__(1024) void k_scan(const int* __restrict__ hist,
                                               int* __restrict__ start) {
  __shared__ int lds[1024];
  int t = threadIdx.x;
  const int CH = (NN + 1023) / 1024;  // 98
  int base = t * CH;
  int lim = base + CH;
  if (lim > NN) lim = NN;
  int s = 0;
  for (int i = base; i < lim; ++i) s += hist[i];
  lds[t] = s;
  __syncthreads();
  for (int off = 1; off < 1024; off <<= 1) {
    int v = (t >= off) ? lds[t - off] : 0;
    __syncthreads();
    lds[t] += v;
    __syncthreads();
  }
  int run = lds[t] - s;  // exclusive prefix of this thread's chunk
  for (int i = base; i < lim; ++i) {
    start[i] = run;
    run += hist[i];
  }
  if (t == 1023) start[NN] = lds[1023];
}

__global__ __launch_bounds__(256) void k_scatter(
    const int* __restrict__ idx, const int* __restrict__ start,
    int* __restrict__ cursor, int* __restrict__ eS, int* __restrict__ srcS) {
  int e = blockIdx.x * 256 + threadIdx.x;
  if (e >= NE) return;
  int dst = idx[NE + e];
  int pos = atomicAdd(&cursor[dst], 1);
  int slot = start[dst] + pos;
  eS[slot] = e;
  srcS[slot] = idx[e];
}

// ---------------------------------------------------------------------------
// One WAVE per node: lane j accumulates H[n][j] = Sigma_e relu(PRA[src][j] +
// c[j] + (ef[e]@B)[j]).  ef rows are wave-uniform broadcast float4 loads;
// B column j lives in 32 VGPRs per lane. Zero atomics, zero cross-lane ops.
// ---------------------------------------------------------------------------
__global__ __launch_bounds__(256) void k_gather(
    const int* __restrict__ eS, const int* __restrict__ srcS,
    const int* __restrict__ start, const float* __restrict__ ef,
    const float* __restrict__ Bm, const float* __restrict__ c,
    const float* __restrict__ PRA, float* __restrict__ Hout) {
  int w = (blockIdx.x * 256 + threadIdx.x) >> 6;
  int lane = threadIdx.x & 63;
  if (w >= NN) return;
  float Bcol[32];
#pragma unroll
  for (int k = 0; k < 32; ++k) Bcol[k] = Bm[k * 64 + lane];
  float cl = c[lane];
  int s0 = start[w], s1 = start[w + 1];
  float Hl = 0.f;
  for (int s = s0; s < s1; ++s) {
    int e = eS[s];
    int src = srcS[s];
    const float4* __restrict__ efp = (const float4*)&ef[(size_t)e * 32];
    float4 efv[8];
#pragma unroll
    for (int u = 0; u < 8; ++u) efv[u] = efp[u];
    float pr = PRA[(size_t)src * 64 + lane];
    float q = cl;
#pragma unroll
    for (int u = 0; u < 8; ++u) {
      q += efv[u].x * Bcol[4 * u + 0];
      q += efv[u].y * Bcol[4 * u + 1];
      q += efv[u].z * Bcol[4 * u + 2];
      q += efv[u].w * Bcol[4 * u + 3];
    }
    Hl += fmaxf(pr + q, 0.f);
  }
  Hout[(size_t)w * 64 + lane] = Hl;
}

// ---------------------------------------------------------------------------
// Lane-per-node: agg = deg*bm2 + H@wm2, then the update MLP.
// All weights uniform-indexed -> scalar loads.
// ---------------------------------------------------------------------------
__global__ __launch_bounds__(256) void k_update2(
    const float* __restrict__ H, const int* __restrict__ start,
    const float* __restrict__ PRU,
    const float* __restrict__ wm2, const float* __restrict__ bm2,
    const float* __restrict__ wu1, const float* __restrict__ bu1,
    const float* __restrict__ wu2, const float* __restrict__ bu2,
    float* __restrict__ out) {
  int n = blockIdx.x * 256 + threadIdx.x;
  if (n >= NN) return;

  float Hr[64];
#pragma unroll
  for (int k = 0; k < 64; k += 4)
    *(float4*)&Hr[k] = *(const float4*)&H[(size_t)n * 64 + k];
  float deg = (float)(start[n + 1] - start[n]);

  float agg[64];
#pragma unroll
  for (int o = 0; o < 64; ++o) agg[o] = deg * bm2[o];
#pragma unroll
  for (int j = 0; j < 64; ++j) {
    float hv = Hr[j];
#pragma unroll
    for (int o = 0; o < 64; ++o) agg[o] += hv * wm2[j * 64 + o];
  }

  float acc[64];
#pragma unroll
  for (int o = 0; o < 64; ++o) acc[o] = bu2[o];

  const float* __restrict__ prs = &PRU[(size_t)n * 64];
#pragma unroll 1
  for (int jc = 0; jc < 64; jc += 16) {
    float q[16];
#pragma unroll
    for (int jj = 0; jj < 16; ++jj) q[jj] = bu1[jc + jj];
#pragma unroll
    for (int k = 0; k < 64; ++k) {
      float av = agg[k];
#pragma unroll
      for (int jj = 0; jj < 16; ++jj) q[jj] += av * wu1[(128 + k) * 64 + jc + jj];
    }
#pragma unroll
    for (int jj = 0; jj < 16; ++jj) {
      float h = fmaxf(prs[jc + jj] + q[jj], 0.f);
#pragma unroll
      for (int o = 0; o < 64; ++o) acc[o] += h * wu2[(jc + jj) * 64 + o];
    }
  }

#pragma unroll
  for (int o = 0; o < 64; o += 4)
    *(float4*)&out[(size_t)n * 64 + o] = make_float4(acc[o], acc[o + 1], acc[o + 2], acc[o + 3]);
}

// ---------------------------------------------------------------------------
// Fallback path (only if ws_size < WS_UNITS*4): round-1 atomic scatter.
// ---------------------------------------------------------------------------
__global__ __launch_bounds__(256) void k_edge_at(
    const int* __restrict__ idx, const float* __restrict__ ef,
    const float* __restrict__ B, const float* __restrict__ c,
    const float* __restrict__ wm2, const float* __restrict__ bm2,
    const float* __restrict__ PRA, float* __restrict__ agg) {
  int e = blockIdx.x * 256 + threadIdx.x;
  if (e >= NE) return;
  int src = idx[e];
  int dst = idx[NE + e];
  float efr[32];
#pragma unroll
  for (int k = 0; k < 32; k += 4)
    *(float4*)&efr[k] = *(const float4*)&ef[(size_t)e * 32 + k];
  float m[64];
#pragma unroll
  for (int o = 0; o < 64; ++o) m[o] = bm2[o];
  const float* __restrict__ prs = &PRA[(size_t)src * 64];
#pragma unroll 1
  for (int jc = 0; jc < 64; jc += 16) {
    float q[16];
#pragma unroll
    for (int jj = 0; jj < 16; ++jj) q[jj] = c[jc + jj];
#pragma unroll
    for (int k = 0; k < 32; ++k) {
      float ev = efr[k];
#pragma unroll
      for (int jj = 0; jj < 16; ++jj) q[jj] += ev * B[k * 64 + jc + jj];
    }
#pragma unroll
    for (int jj = 0; jj < 16; ++jj) {
      float h = fmaxf(prs[jc + jj] + q[jj], 0.f);
#pragma unroll
      for (int o = 0; o < 64; ++o) m[o] += h * wm2[(jc + jj) * 64 + o];
    }
  }
  float* __restrict__ ap = &agg[(size_t)dst * 64];
#pragma unroll
  for (int o = 0; o < 64; ++o) atomicAdd(&ap[o], m[o]);
}

__global__ __launch_bounds__(256) void k_update_at(
    const float* __restrict__ agg, const float* __restrict__ PRU,
    const float* __restrict__ wu1, const float* __restrict__ bu1,
    const float* __restrict__ wu2, const float* __restrict__ bu2,
    float* __restrict__ out) {
  int n = blockIdx.x * 256 + threadIdx.x;
  if (n >= NN) return;
  float ar[64];
#pragma unroll
  for (int k = 0; k < 64; k += 4)
    *(float4*)&ar[k] = *(const float4*)&agg[(size_t)n * 64 + k];
  float acc[64];
#pragma unroll
  for (int o = 0; o < 64; ++o) acc[o] = bu2[o];
  const float* __restrict__ prs = &PRU[(size_t)n * 64];
#pragma unroll 1
  for (int jc = 0; jc < 64; jc += 16) {
    float q[16];
#pragma unroll
    for (int jj = 0; jj < 16; ++jj) q[jj] = bu1[jc + jj];
#pragma unroll
    for (int k = 0; k < 64; ++k) {
      float av = ar[k];
#pragma unroll
      for (int jj = 0; jj < 16; ++jj) q[jj] += av * wu1[(128 + k) * 64 + jc + jj];
    }
#pragma unroll
    for (int jj = 0; jj < 16; ++jj) {
      float h = fmaxf(prs[jc + jj] + q[jj], 0.f);
#pragma unroll
      for (int o = 0; o < 64; ++o) acc[o] += h * wu2[(jc + jj) * 64 + o];
    }
  }
#pragma unroll
  for (int o = 0; o < 64; o += 4)
    *(float4*)&out[(size_t)n * 64 + o] = make_float4(acc[o], acc[o + 1], acc[o + 2], acc[o + 3]);
}

extern "C" void kernel_launch(void* const* d_in, const int* in_sizes, int n_in,
                              void* d_out, int out_size, void* d_ws, size_t ws_size,
                              hipStream_t stream) {
  const float* nf  = (const float*)d_in[0];
  const int*   idx = (const int*)d_in[1];
  const float* ef  = (const float*)d_in[2];
  const float* wn  = (const float*)d_in[3];
  const float* bn  = (const float*)d_in[4];
  const float* we  = (const float*)d_in[5];
  const float* be  = (const float*)d_in[6];
  const float* wm1 = (const float*)d_in[7];
  const float* bm1 = (const float*)d_in[8];
  const float* wm2 = (const float*)d_in[9];
  const float* bm2 = (const float*)d_in[10];
  const float* wu1 = (const float*)d_in[11];
  const float* bu1 = (const float*)d_in[12];
  const float* wu2 = (const float*)d_in[13];
  const float* bu2 = (const float*)d_in[14];
  float* out = (float*)d_out;

  float* ws   = (float*)d_ws;
  float* M    = ws + OFF_M;
  float* B    = ws + OFF_B;
  float* c    = ws + OFF_C;
  float* PRA  = ws + OFF_PRA;
  float* PRU  = ws + OFF_PRU;
  float* H    = ws + OFF_H;      // doubles as agg in fallback
  int*   hist = (int*)(ws + OFF_HIST);
  int*   cur  = (int*)(ws + OFF_CUR);
  int*   strt = (int*)(ws + OFF_STRT);
  int*   eS   = (int*)(ws + OFF_ES);
  int*   srcS = (int*)(ws + OFF_SRCS);

  k_fold<<<(16384 + 2048 + 64 + 255) / 256, 256, 0, stream>>>(
      wn, bn, we, be, wm1, bm1, wu1, M, B, c);
  k_node<<<(NN + 255) / 256, 256, 0, stream>>>(nf, M, PRA, PRU);

  if (ws_size >= (size_t)WS_UNITS * 4) {
    // hist + cursor are adjacent: one memset
    hipMemsetAsync(hist, 0, (size_t)2 * NN * sizeof(int), stream);
    k_hist<<<(NE + 255) / 256, 256, 0, stream>>>(idx, hist);
    k_scan<<<1, 1024, 0, stream>>>(hist, strt);
    k_scatter<<<(NE + 255) / 256, 256, 0, stream>>>(idx, strt, cur, eS, srcS);
    k_gather<<<(NN * 64) / 256, 256, 0, stream>>>(eS, srcS, strt, ef, B, c, PRA, H);
    k_update2<<<(NN + 255) / 256, 256, 0, stream>>>(
        H, strt, PRU, wm2, bm2, wu1, bu1, wu2, bu2, out);
  } else {
    hipMemsetAsync(H, 0, (size_t)NN * 64 * sizeof(float), stream);
    k_edge_at<<<(NE + 255) / 256, 256, 0, stream>>>(idx, ef, B, c, wm2, bm2, PRA, H);
    k_update_at<<<(NN + 255) / 256, 256, 0, stream>>>(
        H, PRU, wu1, bu1, wu2, bu2, out);
  }
}

// Round 5
// 881.220 us; speedup vs baseline: 6.5149x; 1.2170x over previous
//
#include <hip/hip_runtime.h>

#define NN 100000
#define NE 1600000

// ---------------------------------------------------------------------------
// Workspace layout in 4-byte units
// ---------------------------------------------------------------------------
#define OFF_M    0                         // 128*128 folded [A | wu1_top]
#define OFF_B    (OFF_M + 16384)           // 32*64
#define OFF_C    (OFF_B + 2048)            // 64
#define OFF_BSUM (OFF_C + 64)              // 128 block sums (scan)
#define OFF_BOFF (OFF_BSUM + 128)          // 128 block offsets (scan)
#define OFF_PRA  (OFF_BOFF + 128)          // NN*64
#define OFF_PRU  (OFF_PRA + NN * 64)       // NN*64
#define OFF_H    (OFF_PRU + NN * 64)       // NN*64  (agg in fallback)
#define OFF_HIST (OFF_H + NN * 64)         // NN
#define OFF_CUR  (OFF_HIST + NN)           // NN
#define OFF_STRT (OFF_CUR + NN)            // NN+1 (+pad)
#define OFF_SLOT (OFF_STRT + NN + 4)       // NE   (tier1/2: slotOf; tier3: eS)
#define OFF_SRCS (OFF_SLOT + NE)           // NE   (tier3 only: srcS)
#define OFF_HS   OFF_SRCS                  // tier1: NE*64 f32; tier2: NE*64 bf16
#define T3_UNITS (OFF_SRCS + NE)

__device__ __forceinline__ unsigned bfr(float x) {
  unsigned u = __float_as_uint(x);
  return (u + 0x7fffu + ((u >> 16) & 1u)) >> 16;
}
__device__ __forceinline__ float bf2f(unsigned short h) {
  return __uint_as_float(((unsigned)h) << 16);
}

// ---------------------------------------------------------------------------
// Weight folding (same math as round 2)
// ---------------------------------------------------------------------------
__global__ __launch_bounds__(256) void k_fold(
    const float* __restrict__ wn, const float* __restrict__ bn,
    const float* __restrict__ we, const float* __restrict__ be,
    const float* __restrict__ wm1, const float* __restrict__ bm1,
    const float* __restrict__ wu1,
    float* __restrict__ M, float* __restrict__ B, float* __restrict__ c) {
  int t = blockIdx.x * 256 + threadIdx.x;
  if (t < 128 * 128) {
    int k = t >> 7, j = t & 127;
    float acc;
    if (j < 64) {
      acc = 0.f;
      for (int h = 0; h < 64; ++h) acc += wn[k * 64 + h] * wm1[h * 64 + j];
    } else {
      acc = wu1[k * 64 + (j - 64)];
    }
    M[t] = acc;
  } else if (t < 128 * 128 + 32 * 64) {
    int u = t - 128 * 128;
    int k = u >> 6, j = u & 63;
    float acc = 0.f;
    for (int h = 0; h < 64; ++h) acc += we[k * 64 + h] * wm1[(64 + h) * 64 + j];
    B[u] = acc;
  } else if (t < 128 * 128 + 32 * 64 + 64) {
    int j = t - (128 * 128 + 32 * 64);
    float acc = bm1[j];
    for (int h = 0; h < 64; ++h)
      acc += bn[h] * wm1[h * 64 + j] + be[h] * wm1[(64 + h) * 64 + j];
    c[j] = acc;
  }
}

// ---------------------------------------------------------------------------
// PRA[n] = nf[n]@A ; PRU[n] = nf[n]@wu1_top
// ---------------------------------------------------------------------------
__global__ __launch_bounds__(256) void k_node(
    const float* __restrict__ nf, const float* __restrict__ M,
    float* __restrict__ PRA, float* __restrict__ PRU) {
  int n = blockIdx.x * 256 + threadIdx.x;
  if (n >= NN) return;
  const float* __restrict__ row = &nf[(size_t)n * 128];
#pragma unroll 1
  for (int jc = 0; jc < 128; jc += 32) {
    float q[32];
#pragma unroll
    for (int jj = 0; jj < 32; ++jj) q[jj] = 0.f;
#pragma unroll 4
    for (int k = 0; k < 128; k += 4) {
      float4 r4 = *(const float4*)&row[k];
#pragma unroll
      for (int jj = 0; jj < 32; ++jj) q[jj] += r4.x * M[(k + 0) * 128 + jc + jj];
#pragma unroll
      for (int jj = 0; jj < 32; ++jj) q[jj] += r4.y * M[(k + 1) * 128 + jc + jj];
#pragma unroll
      for (int jj = 0; jj < 32; ++jj) q[jj] += r4.z * M[(k + 2) * 128 + jc + jj];
#pragma unroll
      for (int jj = 0; jj < 32; ++jj) q[jj] += r4.w * M[(k + 3) * 128 + jc + jj];
    }
    float* dstp = (jc < 64) ? &PRA[(size_t)n * 64 + jc] : &PRU[(size_t)n * 64 + (jc - 64)];
#pragma unroll
    for (int jj = 0; jj < 32; jj += 4)
      *(float4*)&dstp[jj] = make_float4(q[jj], q[jj + 1], q[jj + 2], q[jj + 3]);
  }
}

// ---------------------------------------------------------------------------
// Counting sort: hist -> 3-phase scan -> scatter
// ---------------------------------------------------------------------------
__global__ __launch_bounds__(256) void k_hist(const int* __restrict__ idx,
                                              int* __restrict__ hist) {
  int e = blockIdx.x * 256 + threadIdx.x;
  if (e < NE) atomicAdd(&hist[idx[NE + e]], 1);
}

__global__ __launch_bounds__(1024) void k_scanA(const int* __restrict__ hist,
                                                int* __restrict__ strt,
                                                int* __restrict__ bsum) {
  __shared__ int lds[1024];
  int t = threadIdx.x;
  int i = blockIdx.x * 1024 + t;
  int v = (i < NN) ? hist[i] : 0;
  lds[t] = v;
  __syncthreads();
  for (int off = 1; off < 1024; off <<= 1) {
    int u = (t >= off) ? lds[t - off] : 0;
    __syncthreads();
    lds[t] += u;
    __syncthreads();
  }
  if (i < NN) strt[i] = lds[t] - v;  // exclusive within block
  if (t == 1023) bsum[blockIdx.x] = lds[1023];
}

__global__ __launch_bounds__(128) void k_scanB(const int* __restrict__ bsum,
                                               int* __restrict__ boff,
                                               int* __restrict__ strt,
                                               int nblocks) {
  __shared__ int lds[128];
  int t = threadIdx.x;
  int v = (t < nblocks) ? bsum[t] : 0;
  lds[t] = v;
  __syncthreads();
  for (int off = 1; off < 128; off <<= 1) {
    int u = (t >= off) ? lds[t - off] : 0;
    __syncthreads();
    lds[t] += u;
    __syncthreads();
  }
  if (t < nblocks) boff[t] = lds[t] - v;
  if (t == 127) strt[NN] = lds[127];
}

__global__ __launch_bounds__(1024) void k_scanC(int* __restrict__ strt,
                                                const int* __restrict__ boff) {
  int i = blockIdx.x * 1024 + threadIdx.x;
  if (i < NN) strt[i] += boff[blockIdx.x];
}

// tier1/2: record destination slot per edge (coalesced write)
__global__ __launch_bounds__(256) void k_scatter_slot(
    const int* __restrict__ idx, const int* __restrict__ strt,
    int* __restrict__ cursor, int* __restrict__ slotOf) {
  int e = blockIdx.x * 256 + threadIdx.x;
  if (e >= NE) return;
  int dst = idx[NE + e];
  int pos = atomicAdd(&cursor[dst], 1);
  slotOf[e] = strt[dst] + pos;
}

// tier3: sorted (edge,src) pairs
__global__ __launch_bounds__(256) void k_scatter_pairs(
    const int* __restrict__ idx, const int* __restrict__ strt,
    int* __restrict__ cursor, int* __restrict__ eS, int* __restrict__ srcS) {
  int e = blockIdx.x * 256 + threadIdx.x;
  if (e >= NE) return;
  int dst = idx[NE + e];
  int pos = atomicAdd(&cursor[dst], 1);
  int slot = strt[dst] + pos;
  eS[slot] = e;
  srcS[slot] = idx[e];
}

// ---------------------------------------------------------------------------
// Tier1/2 k_msg: lane-per-edge in EDGE order (streaming ef), compute
// h = relu(PRA[src] + ef@B + c), scatter-store row to dst-sorted slot.
// FP32 variant.
// ---------------------------------------------------------------------------
__global__ __launch_bounds__(256) void k_msg_f32(
    const int* __restrict__ idx, const int* __restrict__ slotOf,
    const float* __restrict__ ef, const float* __restrict__ Bm,
    const float* __restrict__ c, const float* __restrict__ PRA,
    float* __restrict__ hS) {
  int e = blockIdx.x * 256 + threadIdx.x;
  if (e >= NE) return;
  int src = idx[e];
  int slot = slotOf[e];
  float efr[32];
#pragma unroll
  for (int k = 0; k < 32; k += 4)
    *(float4*)&efr[k] = *(const float4*)&ef[(size_t)e * 32 + k];
  const float* __restrict__ prs = &PRA[(size_t)src * 64];
  float* __restrict__ op = &hS[(size_t)slot * 64];
#pragma unroll 1
  for (int jc = 0; jc < 64; jc += 16) {
    float pr[16];
#pragma unroll
    for (int jj = 0; jj < 16; jj += 4)
      *(float4*)&pr[jj] = *(const float4*)&prs[jc + jj];
    float q[16];
#pragma unroll
    for (int jj = 0; jj < 16; ++jj) q[jj] = c[jc + jj];
#pragma unroll
    for (int k = 0; k < 32; ++k) {
      float ev = efr[k];
#pragma unroll
      for (int jj = 0; jj < 16; ++jj) q[jj] += ev * Bm[k * 64 + jc + jj];
    }
#pragma unroll
    for (int jj = 0; jj < 16; jj += 4) {
      float4 v = make_float4(fmaxf(q[jj] + pr[jj], 0.f),
                             fmaxf(q[jj + 1] + pr[jj + 1], 0.f),
                             fmaxf(q[jj + 2] + pr[jj + 2], 0.f),
                             fmaxf(q[jj + 3] + pr[jj + 3], 0.f));
      *(float4*)&op[jc + jj] = v;
    }
  }
}

// BF16-storage variant (tier2)
__global__ __launch_bounds__(256) void k_msg_bf16(
    const int* __restrict__ idx, const int* __restrict__ slotOf,
    const float* __restrict__ ef, const float* __restrict__ Bm,
    const float* __restrict__ c, const float* __restrict__ PRA,
    unsigned short* __restrict__ hS) {
  int e = blockIdx.x * 256 + threadIdx.x;
  if (e >= NE) return;
  int src = idx[e];
  int slot = slotOf[e];
  float efr[32];
#pragma unroll
  for (int k = 0; k < 32; k += 4)
    *(float4*)&efr[k] = *(const float4*)&ef[(size_t)e * 32 + k];
  const float* __restrict__ prs = &PRA[(size_t)src * 64];
  unsigned* __restrict__ op = (unsigned*)&hS[(size_t)slot * 64];
#pragma unroll 1
  for (int jc = 0; jc < 64; jc += 16) {
    float pr[16];
#pragma unroll
    for (int jj = 0; jj < 16; jj += 4)
      *(float4*)&pr[jj] = *(const float4*)&prs[jc + jj];
    float q[16];
#pragma unroll
    for (int jj = 0; jj < 16; ++jj) q[jj] = c[jc + jj];
#pragma unroll
    for (int k = 0; k < 32; ++k) {
      float ev = efr[k];
#pragma unroll
      for (int jj = 0; jj < 16; ++jj) q[jj] += ev * Bm[k * 64 + jc + jj];
    }
    unsigned w[8];
#pragma unroll
    for (int p = 0; p < 8; ++p) {
      float a = fmaxf(q[2 * p] + pr[2 * p], 0.f);
      float b = fmaxf(q[2 * p + 1] + pr[2 * p + 1], 0.f);
      w[p] = bfr(a) | (bfr(b) << 16);
    }
    *(uint4*)&op[jc / 2] = make_uint4(w[0], w[1], w[2], w[3]);
    *(uint4*)&op[jc / 2 + 4] = make_uint4(w[4], w[5], w[6], w[7]);
  }
}

// ---------------------------------------------------------------------------
// Segment-sum over contiguous sorted rows. Wave per node, lane = dim.
// ---------------------------------------------------------------------------
__global__ __launch_bounds__(256) void k_sum_f32(
    const float* __restrict__ hS, const int* __restrict__ strt,
    float* __restrict__ H) {
  int w = (blockIdx.x * 256 + threadIdx.x) >> 6;
  int lane = threadIdx.x & 63;
  if (w >= NN) return;
  int s0 = strt[w], s1 = strt[w + 1];
  float acc = 0.f;
  int s = s0;
  for (; s + 4 <= s1; s += 4) {
    float a0 = hS[(size_t)(s + 0) * 64 + lane];
    float a1 = hS[(size_t)(s + 1) * 64 + lane];
    float a2 = hS[(size_t)(s + 2) * 64 + lane];
    float a3 = hS[(size_t)(s + 3) * 64 + lane];
    acc += (a0 + a1) + (a2 + a3);
  }
  for (; s < s1; ++s) acc += hS[(size_t)s * 64 + lane];
  H[(size_t)w * 64 + lane] = acc;
}

__global__ __launch_bounds__(256) void k_sum_bf16(
    const unsigned short* __restrict__ hS, const int* __restrict__ strt,
    float* __restrict__ H) {
  int w = (blockIdx.x * 256 + threadIdx.x) >> 6;
  int lane = threadIdx.x & 63;
  if (w >= NN) return;
  int s0 = strt[w], s1 = strt[w + 1];
  float acc = 0.f;
  int s = s0;
  for (; s + 4 <= s1; s += 4) {
    unsigned short a0 = hS[(size_t)(s + 0) * 64 + lane];
    unsigned short a1 = hS[(size_t)(s + 1) * 64 + lane];
    unsigned short a2 = hS[(size_t)(s + 2) * 64 + lane];
    unsigned short a3 = hS[(size_t)(s + 3) * 64 + lane];
    acc += (bf2f(a0) + bf2f(a1)) + (bf2f(a2) + bf2f(a3));
  }
  for (; s < s1; ++s) acc += bf2f(hS[(size_t)s * 64 + lane]);
  H[(size_t)w * 64 + lane] = acc;
}

// ---------------------------------------------------------------------------
// Tier3 k_gather (round-2 version, latency-bound fallback)
// ---------------------------------------------------------------------------
__global__ __launch_bounds__(256) void k_gather(
    const int* __restrict__ eS, const int* __restrict__ srcS,
    const int* __restrict__ start, const float* __restrict__ ef,
    const float* __restrict__ Bm, const float* __restrict__ c,
    const float* __restrict__ PRA, float* __restrict__ Hout) {
  int w = (blockIdx.x * 256 + threadIdx.x) >> 6;
  int lane = threadIdx.x & 63;
  if (w >= NN) return;
  float Bcol[32];
#pragma unroll
  for (int k = 0; k < 32; ++k) Bcol[k] = Bm[k * 64 + lane];
  float cl = c[lane];
  int s0 = start[w], s1 = start[w + 1];
  float Hl = 0.f;
  for (int s = s0; s < s1; ++s) {
    int e = eS[s];
    int src = srcS[s];
    const float4* __restrict__ efp = (const float4*)&ef[(size_t)e * 32];
    float4 efv[8];
#pragma unroll
    for (int u = 0; u < 8; ++u) efv[u] = efp[u];
    float pr = PRA[(size_t)src * 64 + lane];
    float q = cl;
#pragma unroll
    for (int u = 0; u < 8; ++u) {
      q += efv[u].x * Bcol[4 * u + 0];
      q += efv[u].y * Bcol[4 * u + 1];
      q += efv[u].z * Bcol[4 * u + 2];
      q += efv[u].w * Bcol[4 * u + 3];
    }
    Hl += fmaxf(pr + q, 0.f);
  }
  Hout[(size_t)w * 64 + lane] = Hl;
}

// ---------------------------------------------------------------------------
// Final per-node MLP (agg = deg*bm2 + H@wm2, then update MLP)
// ---------------------------------------------------------------------------
__global__ __launch_bounds__(256) void k_update2(
    const float* __restrict__ H, const int* __restrict__ start,
    const float* __restrict__ PRU,
    const float* __restrict__ wm2, const float* __restrict__ bm2,
    const float* __restrict__ wu1, const float* __restrict__ bu1,
    const float* __restrict__ wu2, const float* __restrict__ bu2,
    float* __restrict__ out) {
  int n = blockIdx.x * 256 + threadIdx.x;
  if (n >= NN) return;

  float Hr[64];
#pragma unroll
  for (int k = 0; k < 64; k += 4)
    *(float4*)&Hr[k] = *(const float4*)&H[(size_t)n * 64 + k];
  float deg = (float)(start[n + 1] - start[n]);

  float agg[64];
#pragma unroll
  for (int o = 0; o < 64; ++o) agg[o] = deg * bm2[o];
#pragma unroll
  for (int j = 0; j < 64; ++j) {
    float hv = Hr[j];
#pragma unroll
    for (int o = 0; o < 64; ++o) agg[o] += hv * wm2[j * 64 + o];
  }

  float acc[64];
#pragma unroll
  for (int o = 0; o < 64; ++o) acc[o] = bu2[o];

  const float* __restrict__ prs = &PRU[(size_t)n * 64];
#pragma unroll 1
  for (int jc = 0; jc < 64; jc += 16) {
    float q[16];
#pragma unroll
    for (int jj = 0; jj < 16; ++jj) q[jj] = bu1[jc + jj];
#pragma unroll
    for (int k = 0; k < 64; ++k) {
      float av = agg[k];
#pragma unroll
      for (int jj = 0; jj < 16; ++jj) q[jj] += av * wu1[(128 + k) * 64 + jc + jj];
    }
#pragma unroll
    for (int jj = 0; jj < 16; ++jj) {
      float h = fmaxf(prs[jc + jj] + q[jj], 0.f);
#pragma unroll
      for (int o = 0; o < 64; ++o) acc[o] += h * wu2[(jc + jj) * 64 + o];
    }
  }

#pragma unroll
  for (int o = 0; o < 64; o += 4)
    *(float4*)&out[(size_t)n * 64 + o] = make_float4(acc[o], acc[o + 1], acc[o + 2], acc[o + 3]);
}

// ---------------------------------------------------------------------------
// Tier4: atomic fallback (round-1 style)
// ---------------------------------------------------------------------------
__global__ __launch_bounds__(256) void k_edge_at(
    const int* __restrict__ idx, const float* __restrict__ ef,
    const float* __restrict__ B, const float* __restrict__ c,
    const float* __restrict__ wm2, const float* __restrict__ bm2,
    const float* __restrict__ PRA, float* __restrict__ agg) {
  int e = blockIdx.x * 256 + threadIdx.x;
  if (e >= NE) return;
  int src = idx[e];
  int dst = idx[NE + e];
  float efr[32];
#pragma unroll
  for (int k = 0; k < 32; k += 4)
    *(float4*)&efr[k] = *(const float4*)&ef[(size_t)e * 32 + k];
  float m[64];
#pragma unroll
  for (int o = 0; o < 64; ++o) m[o] = bm2[o];
  const float* __restrict__ prs = &PRA[(size_t)src * 64];
#pragma unroll 1
  for (int jc = 0; jc < 64; jc += 16) {
    float q[16];
#pragma unroll
    for (int jj = 0; jj < 16; ++jj) q[jj] = c[jc + jj];
#pragma unroll
    for (int k = 0; k < 32; ++k) {
      float ev = efr[k];
#pragma unroll
      for (int jj = 0; jj < 16; ++jj) q[jj] += ev * B[k * 64 + jc + jj];
    }
#pragma unroll
    for (int jj = 0; jj < 16; ++jj) {
      float h = fmaxf(prs[jc + jj] + q[jj], 0.f);
#pragma unroll
      for (int o = 0; o < 64; ++o) m[o] += h * wm2[(jc + jj) * 64 + o];
    }
  }
  float* __restrict__ ap = &agg[(size_t)dst * 64];
#pragma unroll
  for (int o = 0; o < 64; ++o) atomicAdd(&ap[o], m[o]);
}

__global__ __launch_bounds__(256) void k_update_at(
    const float* __restrict__ agg, const float* __restrict__ PRU,
    const float* __restrict__ wu1, const float* __restrict__ bu1,
    const float* __restrict__ wu2, const float* __restrict__ bu2,
    float* __restrict__ out) {
  int n = blockIdx.x * 256 + threadIdx.x;
  if (n >= NN) return;
  float ar[64];
#pragma unroll
  for (int k = 0; k < 64; k += 4)
    *(float4*)&ar[k] = *(const float4*)&agg[(size_t)n * 64 + k];
  float acc[64];
#pragma unroll
  for (int o = 0; o < 64; ++o) acc[o] = bu2[o];
  const float* __restrict__ prs = &PRU[(size_t)n * 64];
#pragma unroll 1
  for (int jc = 0; jc < 64; jc += 16) {
    float q[16];
#pragma unroll
    for (int jj = 0; jj < 16; ++jj) q[jj] = bu1[jc + jj];
#pragma unroll
    for (int k = 0; k < 64; ++k) {
      float av = ar[k];
#pragma unroll
      for (int jj = 0; jj < 16; ++jj) q[jj] += av * wu1[(128 + k) * 64 + jc + jj];
    }
#pragma unroll
    for (int jj = 0; jj < 16; ++jj) {
      float h = fmaxf(prs[jc + jj] + q[jj], 0.f);
#pragma unroll
      for (int o = 0; o < 64; ++o) acc[o] += h * wu2[(jc + jj) * 64 + o];
    }
  }
#pragma unroll
  for (int o = 0; o < 64; o += 4)
    *(float4*)&out[(size_t)n * 64 + o] = make_float4(acc[o], acc[o + 1], acc[o + 2], acc[o + 3]);
}

extern "C" void kernel_launch(void* const* d_in, const int* in_sizes, int n_in,
                              void* d_out, int out_size, void* d_ws, size_t ws_size,
                              hipStream_t stream) {
  const float* nf  = (const float*)d_in[0];
  const int*   idx = (const int*)d_in[1];
  const float* ef  = (const float*)d_in[2];
  const float* wn  = (const float*)d_in[3];
  const float* bn  = (const float*)d_in[4];
  const float* we  = (const float*)d_in[5];
  const float* be  = (const float*)d_in[6];
  const float* wm1 = (const float*)d_in[7];
  const float* bm1 = (const float*)d_in[8];
  const float* wm2 = (const float*)d_in[9];
  const float* bm2 = (const float*)d_in[10];
  const float* wu1 = (const float*)d_in[11];
  const float* bu1 = (const float*)d_in[12];
  const float* wu2 = (const float*)d_in[13];
  const float* bu2 = (const float*)d_in[14];
  float* out = (float*)d_out;

  float* ws   = (float*)d_ws;
  float* M    = ws + OFF_M;
  float* B    = ws + OFF_B;
  float* c    = ws + OFF_C;
  int*   bsum = (int*)(ws + OFF_BSUM);
  int*   boff = (int*)(ws + OFF_BOFF);
  float* PRA  = ws + OFF_PRA;
  float* PRU  = ws + OFF_PRU;
  float* H    = ws + OFF_H;
  int*   hist = (int*)(ws + OFF_HIST);
  int*   cur  = (int*)(ws + OFF_CUR);
  int*   strt = (int*)(ws + OFF_STRT);
  int*   slot = (int*)(ws + OFF_SLOT);   // tier1/2 slotOf; tier3 eS
  int*   srcS = (int*)(ws + OFF_SRCS);   // tier3
  float* hSf  = ws + OFF_HS;             // tier1
  unsigned short* hSb = (unsigned short*)(ws + OFF_HS);  // tier2

  const size_t t1_bytes = ((size_t)OFF_HS + (size_t)NE * 64) * 4;
  const size_t t2_bytes = (size_t)OFF_HS * 4 + (size_t)NE * 64 * 2;
  const size_t t3_bytes = (size_t)T3_UNITS * 4;

  const int SCAN_BLOCKS = (NN + 1023) / 1024;  // 98

  k_fold<<<(16384 + 2048 + 64 + 255) / 256, 256, 0, stream>>>(
      wn, bn, we, be, wm1, bm1, wu1, M, B, c);
  k_node<<<(NN + 255) / 256, 256, 0, stream>>>(nf, M, PRA, PRU);

  if (ws_size >= t3_bytes) {
    hipMemsetAsync(hist, 0, (size_t)2 * NN * sizeof(int), stream);
    k_hist<<<(NE + 255) / 256, 256, 0, stream>>>(idx, hist);
    k_scanA<<<SCAN_BLOCKS, 1024, 0, stream>>>(hist, strt, bsum);
    k_scanB<<<1, 128, 0, stream>>>(bsum, boff, strt, SCAN_BLOCKS);
    k_scanC<<<SCAN_BLOCKS, 1024, 0, stream>>>(strt, boff);

    if (ws_size >= t1_bytes) {
      k_scatter_slot<<<(NE + 255) / 256, 256, 0, stream>>>(idx, strt, cur, slot);
      k_msg_f32<<<(NE + 255) / 256, 256, 0, stream>>>(idx, slot, ef, B, c, PRA, hSf);
      k_sum_f32<<<(NN * 64) / 256, 256, 0, stream>>>(hSf, strt, H);
    } else if (ws_size >= t2_bytes) {
      k_scatter_slot<<<(NE + 255) / 256, 256, 0, stream>>>(idx, strt, cur, slot);
      k_msg_bf16<<<(NE + 255) / 256, 256, 0, stream>>>(idx, slot, ef, B, c, PRA, hSb);
      k_sum_bf16<<<(NN * 64) / 256, 256, 0, stream>>>(hSb, strt, H);
    } else {
      k_scatter_pairs<<<(NE + 255) / 256, 256, 0, stream>>>(idx, strt, cur, slot, srcS);
      k_gather<<<(NN * 64) / 256, 256, 0, stream>>>(slot, srcS, strt, ef, B, c, PRA, H);
    }
    k_update2<<<(NN + 255) / 256, 256, 0, stream>>>(
        H, strt, PRU, wm2, bm2, wu1, bu1, wu2, bu2, out);
  } else {
    hipMemsetAsync(H, 0, (size_t)NN * 64 * sizeof(float), stream);
    k_edge_at<<<(NE + 255) / 256, 256, 0, stream>>>(idx, ef, B, c, wm2, bm2, PRA, H);
    k_update_at<<<(NN + 255) / 256, 256, 0, stream>>>(
        H, PRU, wu1, bu1, wu2, bu2, out);
  }
}

// Round 6
// 606.183 us; speedup vs baseline: 9.4708x; 1.4537x over previous
//
#include <hip/hip_runtime.h>

#define NN 100000
#define NE 1600000

// ---------------------------------------------------------------------------
// Workspace layout in 4-byte units (total ~92 MB; proven available)
// ---------------------------------------------------------------------------
#define OFF_M    0                         // 128*128 folded [A | wu1_top]
#define OFF_B    (OFF_M + 16384)           // 32*64
#define OFF_C    (OFF_B + 2048)            // 64
#define OFF_BSUM (OFF_C + 64)              // 128 block sums (scan)
#define OFF_BOFF (OFF_BSUM + 128)          // 128 block offsets (scan)
#define OFF_PRA  (OFF_BOFF + 128)          // NN*64
#define OFF_PRU  (OFF_PRA + NN * 64)       // NN*64
#define OFF_H    (OFF_PRU + NN * 64)       // NN*64  (agg in fallback)
#define OFF_HIST (OFF_H + NN * 64)         // NN
#define OFF_CUR  (OFF_HIST + NN)           // NN
#define OFF_STRT (OFF_CUR + NN)            // NN+1 (+pad)
#define OFF_ESRC (OFF_STRT + NN + 4)       // NE int2 {edge, src} sorted by dst
#define WS_UNITS (OFF_ESRC + 2 * NE)

// ---------------------------------------------------------------------------
// Weight folding:
//   M[128][128]: cols 0-63 = wn@wm1_top ; cols 64-127 = wu1[0:128,:]
//   B[32][64]   = we @ wm1_bot ;  c[64] = bm1 + bn@wm1_top + be@wm1_bot
// ---------------------------------------------------------------------------
__global__ __launch_bounds__(256) void k_fold(
    const float* __restrict__ wn, const float* __restrict__ bn,
    const float* __restrict__ we, const float* __restrict__ be,
    const float* __restrict__ wm1, const float* __restrict__ bm1,
    const float* __restrict__ wu1,
    float* __restrict__ M, float* __restrict__ B, float* __restrict__ c) {
  int t = blockIdx.x * 256 + threadIdx.x;
  if (t < 128 * 128) {
    int k = t >> 7, j = t & 127;
    float acc;
    if (j < 64) {
      acc = 0.f;
      for (int h = 0; h < 64; ++h) acc += wn[k * 64 + h] * wm1[h * 64 + j];
    } else {
      acc = wu1[k * 64 + (j - 64)];
    }
    M[t] = acc;
  } else if (t < 128 * 128 + 32 * 64) {
    int u = t - 128 * 128;
    int k = u >> 6, j = u & 63;
    float acc = 0.f;
    for (int h = 0; h < 64; ++h) acc += we[k * 64 + h] * wm1[(64 + h) * 64 + j];
    B[u] = acc;
  } else if (t < 128 * 128 + 32 * 64 + 64) {
    int j = t - (128 * 128 + 32 * 64);
    float acc = bm1[j];
    for (int h = 0; h < 64; ++h)
      acc += bn[h] * wm1[h * 64 + j] + be[h] * wm1[(64 + h) * 64 + j];
    c[j] = acc;
  }
}

// ---------------------------------------------------------------------------
// PRA[n] = nf[n]@A ; PRU[n] = nf[n]@wu1_top  (lane-per-node, scalar weights)
// ---------------------------------------------------------------------------
__global__ __launch_bounds__(256) void k_node(
    const float* __restrict__ nf, const float* __restrict__ M,
    float* __restrict__ PRA, float* __restrict__ PRU) {
  int n = blockIdx.x * 256 + threadIdx.x;
  if (n >= NN) return;
  const float* __restrict__ row = &nf[(size_t)n * 128];
#pragma unroll 1
  for (int jc = 0; jc < 128; jc += 32) {
    float q[32];
#pragma unroll
    for (int jj = 0; jj < 32; ++jj) q[jj] = 0.f;
#pragma unroll 4
    for (int k = 0; k < 128; k += 4) {
      float4 r4 = *(const float4*)&row[k];
#pragma unroll
      for (int jj = 0; jj < 32; ++jj) q[jj] += r4.x * M[(k + 0) * 128 + jc + jj];
#pragma unroll
      for (int jj = 0; jj < 32; ++jj) q[jj] += r4.y * M[(k + 1) * 128 + jc + jj];
#pragma unroll
      for (int jj = 0; jj < 32; ++jj) q[jj] += r4.z * M[(k + 2) * 128 + jc + jj];
#pragma unroll
      for (int jj = 0; jj < 32; ++jj) q[jj] += r4.w * M[(k + 3) * 128 + jc + jj];
    }
    float* dstp = (jc < 64) ? &PRA[(size_t)n * 64 + jc] : &PRU[(size_t)n * 64 + (jc - 64)];
#pragma unroll
    for (int jj = 0; jj < 32; jj += 4)
      *(float4*)&dstp[jj] = make_float4(q[jj], q[jj + 1], q[jj + 2], q[jj + 3]);
  }
}

// ---------------------------------------------------------------------------
// Counting sort: hist -> 3-phase scan -> scatter {edge,src} pairs
// ---------------------------------------------------------------------------
__global__ __launch_bounds__(256) void k_hist(const int* __restrict__ idx,
                                              int* __restrict__ hist) {
  int e = blockIdx.x * 256 + threadIdx.x;
  if (e < NE) atomicAdd(&hist[idx[NE + e]], 1);
}

__global__ __launch_bounds__(1024) void k_scanA(const int* __restrict__ hist,
                                                int* __restrict__ strt,
                                                int* __restrict__ bsum) {
  __shared__ int lds[1024];
  int t = threadIdx.x;
  int i = blockIdx.x * 1024 + t;
  int v = (i < NN) ? hist[i] : 0;
  lds[t] = v;
  __syncthreads();
  for (int off = 1; off < 1024; off <<= 1) {
    int u = (t >= off) ? lds[t - off] : 0;
    __syncthreads();
    lds[t] += u;
    __syncthreads();
  }
  if (i < NN) strt[i] = lds[t] - v;
  if (t == 1023) bsum[blockIdx.x] = lds[1023];
}

__global__ __launch_bounds__(128) void k_scanB(const int* __restrict__ bsum,
                                               int* __restrict__ boff,
                                               int* __restrict__ strt,
                                               int nblocks) {
  __shared__ int lds[128];
  int t = threadIdx.x;
  int v = (t < nblocks) ? bsum[t] : 0;
  lds[t] = v;
  __syncthreads();
  for (int off = 1; off < 128; off <<= 1) {
    int u = (t >= off) ? lds[t - off] : 0;
    __syncthreads();
    lds[t] += u;
    __syncthreads();
  }
  if (t < nblocks) boff[t] = lds[t] - v;
  if (t == 127) strt[NN] = lds[127];
}

__global__ __launch_bounds__(1024) void k_scanC(int* __restrict__ strt,
                                                const int* __restrict__ boff) {
  int i = blockIdx.x * 1024 + threadIdx.x;
  if (i < NN) strt[i] += boff[blockIdx.x];
}

__global__ __launch_bounds__(256) void k_scatter_pairs2(
    const int* __restrict__ idx, const int* __restrict__ strt,
    int* __restrict__ cursor, int2* __restrict__ esrc) {
  int e = blockIdx.x * 256 + threadIdx.x;
  if (e >= NE) return;
  int dst = idx[NE + e];
  int pos = atomicAdd(&cursor[dst], 1);
  int2 v;
  v.x = e;
  v.y = idx[e];
  esrc[strt[dst] + pos] = v;
}

// ---------------------------------------------------------------------------
// Fused message+aggregate: one WAVE per node, lane = hidden dim.
// 3-stage pipeline over 4-edge batches:
//   stage A (b+2): broadcast esrc loads (no indirection)
//   stage B (b+1): issue ef float2 (coalesced per row) + PRA loads
//   stage C (b)  : ds_write staged ef -> wave-private LDS, broadcast-read,
//                  128 FMA, acc += relu(PRA + ef@B + c)
// ---------------------------------------------------------------------------
__global__ __launch_bounds__(256) void k_gather3(
    const int2* __restrict__ esrc, const int* __restrict__ strt,
    const float* __restrict__ ef, const float* __restrict__ Bm,
    const float* __restrict__ c, const float* __restrict__ PRA,
    float* __restrict__ H) {
  __shared__ float efb[4][2][4][32];  // [wave][dbuf][edge][k]
  int wib = threadIdx.x >> 6;
  int lane = threadIdx.x & 63;
  int n = blockIdx.x * 4 + wib;
  if (n >= NN) return;

  float Bcol[32];
#pragma unroll
  for (int k = 0; k < 32; ++k) Bcol[k] = Bm[k * 64 + lane];
  float cl = c[lane];

  int s0 = strt[n], s1 = strt[n + 1];
  int nfull = (s1 - s0) >> 2;
  float acc = 0.f;

  int jj = lane >> 4;          // which edge of the batch this lane stages
  int k0 = (lane & 15) * 2;    // which 2 elements of the 32-float row

  float2 stg = make_float2(0.f, 0.f);
  float pc0 = 0.f, pc1 = 0.f, pc2 = 0.f, pc3 = 0.f;
  float pn0 = 0.f, pn1 = 0.f, pn2 = 0.f, pn3 = 0.f;
  int2 nb0, nb1, nb2, nb3;
  nb0 = nb1 = nb2 = nb3 = make_int2(0, 0);

  if (nfull > 0) {
    int2 a0 = esrc[s0], a1 = esrc[s0 + 1], a2 = esrc[s0 + 2], a3 = esrc[s0 + 3];
    int em = lane < 32 ? (lane < 16 ? a0.x : a1.x) : (lane < 48 ? a2.x : a3.x);
    stg = *(const float2*)&ef[(size_t)em * 32 + k0];
    pc0 = PRA[(size_t)a0.y * 64 + lane];
    pc1 = PRA[(size_t)a1.y * 64 + lane];
    pc2 = PRA[(size_t)a2.y * 64 + lane];
    pc3 = PRA[(size_t)a3.y * 64 + lane];
    if (nfull > 1) {
      nb0 = esrc[s0 + 4]; nb1 = esrc[s0 + 5];
      nb2 = esrc[s0 + 6]; nb3 = esrc[s0 + 7];
    }
  }

#pragma unroll 1
  for (int b = 0; b < nfull; ++b) {
    float(*buf)[32] = efb[wib][b & 1];
    // stage C write: batch-b ef (loaded last iteration / prologue) into LDS
    *(float2*)&buf[jj][k0] = stg;

    // stage B: issue global loads for batch b+1
    if (b + 1 < nfull) {
      int em = lane < 32 ? (lane < 16 ? nb0.x : nb1.x) : (lane < 48 ? nb2.x : nb3.x);
      stg = *(const float2*)&ef[(size_t)em * 32 + k0];
      pn0 = PRA[(size_t)nb0.y * 64 + lane];
      pn1 = PRA[(size_t)nb1.y * 64 + lane];
      pn2 = PRA[(size_t)nb2.y * 64 + lane];
      pn3 = PRA[(size_t)nb3.y * 64 + lane];
    }
    // stage A: broadcast esrc loads for batch b+2
    if (b + 2 < nfull) {
      int sb = s0 + 4 * (b + 2);
      nb0 = esrc[sb]; nb1 = esrc[sb + 1]; nb2 = esrc[sb + 2]; nb3 = esrc[sb + 3];
    }

    // compute batch b: broadcast LDS reads + FMA
    float q0 = cl, q1 = cl, q2 = cl, q3 = cl;
#pragma unroll
    for (int u = 0; u < 8; ++u) {
      float4 v0 = *(const float4*)&buf[0][u * 4];
      float4 v1 = *(const float4*)&buf[1][u * 4];
      float4 v2 = *(const float4*)&buf[2][u * 4];
      float4 v3 = *(const float4*)&buf[3][u * 4];
      q0 += v0.x * Bcol[4 * u] + v0.y * Bcol[4 * u + 1] + v0.z * Bcol[4 * u + 2] + v0.w * Bcol[4 * u + 3];
      q1 += v1.x * Bcol[4 * u] + v1.y * Bcol[4 * u + 1] + v1.z * Bcol[4 * u + 2] + v1.w * Bcol[4 * u + 3];
      q2 += v2.x * Bcol[4 * u] + v2.y * Bcol[4 * u + 1] + v2.z * Bcol[4 * u + 2] + v2.w * Bcol[4 * u + 3];
      q3 += v3.x * Bcol[4 * u] + v3.y * Bcol[4 * u + 1] + v3.z * Bcol[4 * u + 2] + v3.w * Bcol[4 * u + 3];
    }
    acc += fmaxf(q0 + pc0, 0.f) + fmaxf(q1 + pc1, 0.f) +
           fmaxf(q2 + pc2, 0.f) + fmaxf(q3 + pc3, 0.f);
    pc0 = pn0; pc1 = pn1; pc2 = pn2; pc3 = pn3;
  }

  // tail: remaining 0-3 edges, direct broadcast reads
  for (int s = s0 + nfull * 4; s < s1; ++s) {
    int2 es = esrc[s];
    const float* __restrict__ efp = &ef[(size_t)es.x * 32];
    float q = cl;
#pragma unroll
    for (int u = 0; u < 8; ++u) {
      float4 v = *(const float4*)&efp[u * 4];
      q += v.x * Bcol[4 * u] + v.y * Bcol[4 * u + 1] + v.z * Bcol[4 * u + 2] + v.w * Bcol[4 * u + 3];
    }
    acc += fmaxf(q + PRA[(size_t)es.y * 64 + lane], 0.f);
  }

  H[(size_t)n * 64 + lane] = acc;
}

// ---------------------------------------------------------------------------
// Final per-node MLP: agg = deg*bm2 + H@wm2, then update MLP
// ---------------------------------------------------------------------------
__global__ __launch_bounds__(256) void k_update2(
    const float* __restrict__ H, const int* __restrict__ start,
    const float* __restrict__ PRU,
    const float* __restrict__ wm2, const float* __restrict__ bm2,
    const float* __restrict__ wu1, const float* __restrict__ bu1,
    const float* __restrict__ wu2, const float* __restrict__ bu2,
    float* __restrict__ out) {
  int n = blockIdx.x * 256 + threadIdx.x;
  if (n >= NN) return;

  float Hr[64];
#pragma unroll
  for (int k = 0; k < 64; k += 4)
    *(float4*)&Hr[k] = *(const float4*)&H[(size_t)n * 64 + k];
  float deg = (float)(start[n + 1] - start[n]);

  float agg[64];
#pragma unroll
  for (int o = 0; o < 64; ++o) agg[o] = deg * bm2[o];
#pragma unroll
  for (int j = 0; j < 64; ++j) {
    float hv = Hr[j];
#pragma unroll
    for (int o = 0; o < 64; ++o) agg[o] += hv * wm2[j * 64 + o];
  }

  float acc[64];
#pragma unroll
  for (int o = 0; o < 64; ++o) acc[o] = bu2[o];

  const float* __restrict__ prs = &PRU[(size_t)n * 64];
#pragma unroll 1
  for (int jc = 0; jc < 64; jc += 16) {
    float q[16];
#pragma unroll
    for (int jj = 0; jj < 16; ++jj) q[jj] = bu1[jc + jj];
#pragma unroll
    for (int k = 0; k < 64; ++k) {
      float av = agg[k];
#pragma unroll
      for (int jj = 0; jj < 16; ++jj) q[jj] += av * wu1[(128 + k) * 64 + jc + jj];
    }
#pragma unroll
    for (int jj = 0; jj < 16; ++jj) {
      float h = fmaxf(prs[jc + jj] + q[jj], 0.f);
#pragma unroll
      for (int o = 0; o < 64; ++o) acc[o] += h * wu2[(jc + jj) * 64 + o];
    }
  }

#pragma unroll
  for (int o = 0; o < 64; o += 4)
    *(float4*)&out[(size_t)n * 64 + o] = make_float4(acc[o], acc[o + 1], acc[o + 2], acc[o + 3]);
}

// ---------------------------------------------------------------------------
// Fallback (ws too small): round-1 atomic scatter
// ---------------------------------------------------------------------------
__global__ __launch_bounds__(256) void k_edge_at(
    const int* __restrict__ idx, const float* __restrict__ ef,
    const float* __restrict__ B, const float* __restrict__ c,
    const float* __restrict__ wm2, const float* __restrict__ bm2,
    const float* __restrict__ PRA, float* __restrict__ agg) {
  int e = blockIdx.x * 256 + threadIdx.x;
  if (e >= NE) return;
  int src = idx[e];
  int dst = idx[NE + e];
  float efr[32];
#pragma unroll
  for (int k = 0; k < 32; k += 4)
    *(float4*)&efr[k] = *(const float4*)&ef[(size_t)e * 32 + k];
  float m[64];
#pragma unroll
  for (int o = 0; o < 64; ++o) m[o] = bm2[o];
  const float* __restrict__ prs = &PRA[(size_t)src * 64];
#pragma unroll 1
  for (int jc = 0; jc < 64; jc += 16) {
    float q[16];
#pragma unroll
    for (int jj = 0; jj < 16; ++jj) q[jj] = c[jc + jj];
#pragma unroll
    for (int k = 0; k < 32; ++k) {
      float ev = efr[k];
#pragma unroll
      for (int jj = 0; jj < 16; ++jj) q[jj] += ev * B[k * 64 + jc + jj];
    }
#pragma unroll
    for (int jj = 0; jj < 16; ++jj) {
      float h = fmaxf(prs[jc + jj] + q[jj], 0.f);
#pragma unroll
      for (int o = 0; o < 64; ++o) m[o] += h * wm2[(jc + jj) * 64 + o];
    }
  }
  float* __restrict__ ap = &agg[(size_t)dst * 64];
#pragma unroll
  for (int o = 0; o < 64; ++o) atomicAdd(&ap[o], m[o]);
}

__global__ __launch_bounds__(256) void k_update_at(
    const float* __restrict__ agg, const float* __restrict__ PRU,
    const float* __restrict__ wu1, const float* __restrict__ bu1,
    const float* __restrict__ wu2, const float* __restrict__ bu2,
    float* __restrict__ out) {
  int n = blockIdx.x * 256 + threadIdx.x;
  if (n >= NN) return;
  float ar[64];
#pragma unroll
  for (int k = 0; k < 64; k += 4)
    *(float4*)&ar[k] = *(const float4*)&agg[(size_t)n * 64 + k];
  float acc[64];
#pragma unroll
  for (int o = 0; o < 64; ++o) acc[o] = bu2[o];
  const float* __restrict__ prs = &PRU[(size_t)n * 64];
#pragma unroll 1
  for (int jc = 0; jc < 64; jc += 16) {
    float q[16];
#pragma unroll
    for (int jj = 0; jj < 16; ++jj) q[jj] = bu1[jc + jj];
#pragma unroll
    for (int k = 0; k < 64; ++k) {
      float av = ar[k];
#pragma unroll
      for (int jj = 0; jj < 16; ++jj) q[jj] += av * wu1[(128 + k) * 64 + jc + jj];
    }
#pragma unroll
    for (int jj = 0; jj < 16; ++jj) {
      float h = fmaxf(prs[jc + jj] + q[jj], 0.f);
#pragma unroll
      for (int o = 0; o < 64; ++o) acc[o] += h * wu2[(jc + jj) * 64 + o];
    }
  }
#pragma unroll
  for (int o = 0; o < 64; o += 4)
    *(float4*)&out[(size_t)n * 64 + o] = make_float4(acc[o], acc[o + 1], acc[o + 2], acc[o + 3]);
}

extern "C" void kernel_launch(void* const* d_in, const int* in_sizes, int n_in,
                              void* d_out, int out_size, void* d_ws, size_t ws_size,
                              hipStream_t stream) {
  const float* nf  = (const float*)d_in[0];
  const int*   idx = (const int*)d_in[1];
  const float* ef  = (const float*)d_in[2];
  const float* wn  = (const float*)d_in[3];
  const float* bn  = (const float*)d_in[4];
  const float* we  = (const float*)d_in[5];
  const float* be  = (const float*)d_in[6];
  const float* wm1 = (const float*)d_in[7];
  const float* bm1 = (const float*)d_in[8];
  const float* wm2 = (const float*)d_in[9];
  const float* bm2 = (const float*)d_in[10];
  const float* wu1 = (const float*)d_in[11];
  const float* bu1 = (const float*)d_in[12];
  const float* wu2 = (const float*)d_in[13];
  const float* bu2 = (const float*)d_in[14];
  float* out = (float*)d_out;

  float* ws   = (float*)d_ws;
  float* M    = ws + OFF_M;
  float* B    = ws + OFF_B;
  float* c    = ws + OFF_C;
  int*   bsum = (int*)(ws + OFF_BSUM);
  int*   boff = (int*)(ws + OFF_BOFF);
  float* PRA  = ws + OFF_PRA;
  float* PRU  = ws + OFF_PRU;
  float* H    = ws + OFF_H;
  int*   hist = (int*)(ws + OFF_HIST);
  int*   cur  = (int*)(ws + OFF_CUR);
  int*   strt = (int*)(ws + OFF_STRT);
  int2*  esrc = (int2*)(ws + OFF_ESRC);

  const int SCAN_BLOCKS = (NN + 1023) / 1024;  // 98

  k_fold<<<(16384 + 2048 + 64 + 255) / 256, 256, 0, stream>>>(
      wn, bn, we, be, wm1, bm1, wu1, M, B, c);
  k_node<<<(NN + 255) / 256, 256, 0, stream>>>(nf, M, PRA, PRU);

  if (ws_size >= (size_t)WS_UNITS * 4) {
    hipMemsetAsync(hist, 0, (size_t)2 * NN * sizeof(int), stream);
    k_hist<<<(NE + 255) / 256, 256, 0, stream>>>(idx, hist);
    k_scanA<<<SCAN_BLOCKS, 1024, 0, stream>>>(hist, strt, bsum);
    k_scanB<<<1, 128, 0, stream>>>(bsum, boff, strt, SCAN_BLOCKS);
    k_scanC<<<SCAN_BLOCKS, 1024, 0, stream>>>(strt, boff);
    k_scatter_pairs2<<<(NE + 255) / 256, 256, 0, stream>>>(idx, strt, cur, esrc);
    k_gather3<<<(NN + 3) / 4, 256, 0, stream>>>(esrc, strt, ef, B, c, PRA, H);
    k_update2<<<(NN + 255) / 256, 256, 0, stream>>>(
        H, strt, PRU, wm2, bm2, wu1, bu1, wu2, bu2, out);
  } else {
    hipMemsetAsync(H, 0, (size_t)NN * 64 * sizeof(float), stream);
    k_edge_at<<<(NE + 255) / 256, 256, 0, stream>>>(idx, ef, B, c, wm2, bm2, PRA, H);
    k_update_at<<<(NN + 255) / 256, 256, 0, stream>>>(
        H, PRU, wu1, bu1, wu2, bu2, out);
  }
}

// Round 7
// 548.260 us; speedup vs baseline: 10.4713x; 1.1056x over previous
//
#include <hip/hip_runtime.h>

#define NN 100000
#define NE 1600000

// ---------------------------------------------------------------------------
// Workspace layout in 4-byte units (~92 MB total; proven available)
// ---------------------------------------------------------------------------
#define OFF_M    0                         // 128*128 folded [A | wu1_top]
#define OFF_B    (OFF_M + 16384)           // 32*64   we @ wm1_bot
#define OFF_C    (OFF_B + 2048)            // 64      folded msg bias
#define OFF_W2U  (OFF_C + 64)              // 64*64   wm2 @ wu1_bot
#define OFF_D2   (OFF_W2U + 4096)          // 64      bm2 @ wu1_bot
#define OFF_BSUM (OFF_D2 + 64)             // 128 block sums (scan)
#define OFF_BOFF (OFF_BSUM + 128)          // 128 block offsets (scan)
#define OFF_PRA  (OFF_BOFF + 128)          // NN*64
#define OFF_PRU  (OFF_PRA + NN * 64)       // NN*64
#define OFF_H    (OFF_PRU + NN * 64)       // NN*64  (agg in fallback)
#define OFF_HIST (OFF_H + NN * 64)         // NN
#define OFF_CUR  (OFF_HIST + NN)           // NN
#define OFF_STRT (OFF_CUR + NN)            // NN+1 (+pad)
#define OFF_ESRC (OFF_STRT + NN + 4)       // NE int2 {edge, src} sorted by dst
#define WS_UNITS (OFF_ESRC + 2 * NE)

__device__ __forceinline__ int rfl(int x) {
  return __builtin_amdgcn_readfirstlane(x);
}

// ---------------------------------------------------------------------------
// Weight folding:
//   M[128][128]: cols 0-63 = wn@wm1_top ; cols 64-127 = wu1[0:128,:]
//   B[32][64] = we@wm1_bot ; c = bm1 + bn@wm1_top + be@wm1_bot
//   W2U[64][64] = wm2 @ wu1_bot ; d2 = bm2 @ wu1_bot
// ---------------------------------------------------------------------------
__global__ __launch_bounds__(256) void k_fold(
    const float* __restrict__ wn, const float* __restrict__ bn,
    const float* __restrict__ we, const float* __restrict__ be,
    const float* __restrict__ wm1, const float* __restrict__ bm1,
    const float* __restrict__ wm2, const float* __restrict__ bm2,
    const float* __restrict__ wu1,
    float* __restrict__ M, float* __restrict__ B, float* __restrict__ c,
    float* __restrict__ W2U, float* __restrict__ d2) {
  int t = blockIdx.x * 256 + threadIdx.x;
  if (t < 16384) {
    int k = t >> 7, j = t & 127;
    float acc;
    if (j < 64) {
      acc = 0.f;
      for (int h = 0; h < 64; ++h) acc += wn[k * 64 + h] * wm1[h * 64 + j];
    } else {
      acc = wu1[k * 64 + (j - 64)];
    }
    M[t] = acc;
  } else if (t < 16384 + 2048) {
    int u = t - 16384;
    int k = u >> 6, j = u & 63;
    float acc = 0.f;
    for (int h = 0; h < 64; ++h) acc += we[k * 64 + h] * wm1[(64 + h) * 64 + j];
    B[u] = acc;
  } else if (t < 16384 + 2048 + 64) {
    int j = t - (16384 + 2048);
    float acc = bm1[j];
    for (int h = 0; h < 64; ++h)
      acc += bn[h] * wm1[h * 64 + j] + be[h] * wm1[(64 + h) * 64 + j];
    c[j] = acc;
  } else if (t < 16384 + 2048 + 64 + 4096) {
    int u = t - (16384 + 2048 + 64);
    int k = u >> 6, j = u & 63;
    float acc = 0.f;
    for (int h = 0; h < 64; ++h) acc += wm2[k * 64 + h] * wu1[(128 + h) * 64 + j];
    W2U[u] = acc;
  } else if (t < 16384 + 2048 + 64 + 4096 + 64) {
    int j = t - (16384 + 2048 + 64 + 4096);
    float acc = 0.f;
    for (int h = 0; h < 64; ++h) acc += bm2[h] * wu1[(128 + h) * 64 + j];
    d2[j] = acc;
  }
}

// ---------------------------------------------------------------------------
// PRA[n] = nf[n]@A ; PRU[n] = nf[n]@wu1_top  (lane-per-node, scalar weights)
// ---------------------------------------------------------------------------
__global__ __launch_bounds__(256) void k_node(
    const float* __restrict__ nf, const float* __restrict__ M,
    float* __restrict__ PRA, float* __restrict__ PRU) {
  int n = blockIdx.x * 256 + threadIdx.x;
  if (n >= NN) return;
  const float* __restrict__ row = &nf[(size_t)n * 128];
#pragma unroll 1
  for (int jc = 0; jc < 128; jc += 32) {
    float q[32];
#pragma unroll
    for (int jj = 0; jj < 32; ++jj) q[jj] = 0.f;
#pragma unroll 4
    for (int k = 0; k < 128; k += 4) {
      float4 r4 = *(const float4*)&row[k];
#pragma unroll
      for (int jj = 0; jj < 32; ++jj) q[jj] += r4.x * M[(k + 0) * 128 + jc + jj];
#pragma unroll
      for (int jj = 0; jj < 32; ++jj) q[jj] += r4.y * M[(k + 1) * 128 + jc + jj];
#pragma unroll
      for (int jj = 0; jj < 32; ++jj) q[jj] += r4.z * M[(k + 2) * 128 + jc + jj];
#pragma unroll
      for (int jj = 0; jj < 32; ++jj) q[jj] += r4.w * M[(k + 3) * 128 + jc + jj];
    }
    float* dstp = (jc < 64) ? &PRA[(size_t)n * 64 + jc] : &PRU[(size_t)n * 64 + (jc - 64)];
#pragma unroll
    for (int jj = 0; jj < 32; jj += 4)
      *(float4*)&dstp[jj] = make_float4(q[jj], q[jj + 1], q[jj + 2], q[jj + 3]);
  }
}

// ---------------------------------------------------------------------------
// Counting sort: hist -> 3-phase scan -> scatter {edge,src} pairs
// ---------------------------------------------------------------------------
__global__ __launch_bounds__(256) void k_hist(const int* __restrict__ idx,
                                              int* __restrict__ hist) {
  int e = blockIdx.x * 256 + threadIdx.x;
  if (e < NE) atomicAdd(&hist[idx[NE + e]], 1);
}

__global__ __launch_bounds__(1024) void k_scanA(const int* __restrict__ hist,
                                                int* __restrict__ strt,
                                                int* __restrict__ bsum) {
  __shared__ int lds[1024];
  int t = threadIdx.x;
  int i = blockIdx.x * 1024 + t;
  int v = (i < NN) ? hist[i] : 0;
  lds[t] = v;
  __syncthreads();
  for (int off = 1; off < 1024; off <<= 1) {
    int u = (t >= off) ? lds[t - off] : 0;
    __syncthreads();
    lds[t] += u;
    __syncthreads();
  }
  if (i < NN) strt[i] = lds[t] - v;
  if (t == 1023) bsum[blockIdx.x] = lds[1023];
}

__global__ __launch_bounds__(128) void k_scanB(const int* __restrict__ bsum,
                                               int* __restrict__ boff,
                                               int* __restrict__ strt,
                                               int nblocks) {
  __shared__ int lds[128];
  int t = threadIdx.x;
  int v = (t < nblocks) ? bsum[t] : 0;
  lds[t] = v;
  __syncthreads();
  for (int off = 1; off < 128; off <<= 1) {
    int u = (t >= off) ? lds[t - off] : 0;
    __syncthreads();
    lds[t] += u;
    __syncthreads();
  }
  if (t < nblocks) boff[t] = lds[t] - v;
  if (t == 127) strt[NN] = lds[127];
}

__global__ __launch_bounds__(1024) void k_scanC(int* __restrict__ strt,
                                                const int* __restrict__ boff) {
  int i = blockIdx.x * 1024 + threadIdx.x;
  if (i < NN) strt[i] += boff[blockIdx.x];
}

__global__ __launch_bounds__(256) void k_scatter_pairs2(
    const int* __restrict__ idx, const int* __restrict__ strt,
    int* __restrict__ cursor, int2* __restrict__ esrc) {
  int e = blockIdx.x * 256 + threadIdx.x;
  if (e >= NE) return;
  int dst = idx[NE + e];
  int pos = atomicAdd(&cursor[dst], 1);
  int2 v;
  v.x = e;
  v.y = idx[e];
  esrc[strt[dst] + pos] = v;
}

// ---------------------------------------------------------------------------
// Fused message+aggregate v2: one WAVE per node; edges processed in PAIRS.
// Lanes 0-31 = edge A, lanes 32-63 = edge B; each lane owns outputs
// {2*l5, 2*l5+1} (float2, pk-fma-able). Wave-uniform values scalarized via
// readfirstlane -> saddr loads. ef staged through wave-private LDS
// (1 coalesced float/lane). Depth-1 prefetch; cross-half shfl_xor combine.
// ---------------------------------------------------------------------------
__global__ __launch_bounds__(256) void k_gather4(
    const int2* __restrict__ esrc, const int* __restrict__ strt,
    const float* __restrict__ ef, const float* __restrict__ Bm,
    const float* __restrict__ c, const float* __restrict__ PRA,
    float* __restrict__ H) {
  __shared__ float efb[4][2][2][32];  // [wave][dbuf][half][k]
  int wib = threadIdx.x >> 6;
  int lane = threadIdx.x & 63;
  int half = lane >> 5;
  int l5 = lane & 31;
  int n = rfl(blockIdx.x * 4 + wib);
  if (n >= NN) return;

  float2 Bc[32];
#pragma unroll
  for (int k = 0; k < 32; ++k) Bc[k] = *(const float2*)&Bm[k * 64 + 2 * l5];
  float clx = c[2 * l5], cly = c[2 * l5 + 1];

  int s0 = rfl(strt[n]);
  int s1 = rfl(strt[n + 1]);
  int npairs = (s1 - s0) >> 1;

  float accx = 0.f, accy = 0.f;
  float efv = 0.f;
  float prx = 0.f, pry = 0.f;

  if (npairs > 0) {
    int2 pa = esrc[s0], pb = esrc[s0 + 1];
    int e0 = rfl(pa.x), sr0 = rfl(pa.y), e1 = rfl(pb.x), sr1 = rfl(pb.y);
    int em = half ? e1 : e0;
    int sm = half ? sr1 : sr0;
    efv = ef[(size_t)em * 32 + l5];
    float2 p2 = *(const float2*)&PRA[(size_t)sm * 64 + 2 * l5];
    prx = p2.x; pry = p2.y;
  }

#pragma unroll 1
  for (int b = 0; b < npairs; ++b) {
    float* buf = &efb[wib][b & 1][0][0];
    buf[half * 32 + l5] = efv;  // stage current pair's ef rows
    float pcx = prx, pcy = pry;

    if (b + 1 < npairs) {  // prefetch next pair
      int sb = s0 + 2 * (b + 1);
      int2 pa = esrc[sb], pb = esrc[sb + 1];
      int e0 = rfl(pa.x), sr0 = rfl(pa.y), e1 = rfl(pb.x), sr1 = rfl(pb.y);
      int em = half ? e1 : e0;
      int sm = half ? sr1 : sr0;
      efv = ef[(size_t)em * 32 + l5];
      float2 p2 = *(const float2*)&PRA[(size_t)sm * 64 + 2 * l5];
      prx = p2.x; pry = p2.y;
    }

    const float* bb = &efb[wib][b & 1][half][0];
    float qx = clx, qy = cly;
#pragma unroll
    for (int u = 0; u < 8; ++u) {
      float4 v = *(const float4*)&bb[4 * u];
      qx = fmaf(v.x, Bc[4 * u + 0].x, qx); qy = fmaf(v.x, Bc[4 * u + 0].y, qy);
      qx = fmaf(v.y, Bc[4 * u + 1].x, qx); qy = fmaf(v.y, Bc[4 * u + 1].y, qy);
      qx = fmaf(v.z, Bc[4 * u + 2].x, qx); qy = fmaf(v.z, Bc[4 * u + 2].y, qy);
      qx = fmaf(v.w, Bc[4 * u + 3].x, qx); qy = fmaf(v.w, Bc[4 * u + 3].y, qy);
    }
    accx += fmaxf(qx + pcx, 0.f);
    accy += fmaxf(qy + pcy, 0.f);
  }

  // tail: odd remaining edge, half 0 accumulates only
  if ((s1 - s0) & 1) {
    int2 es = esrc[s1 - 1];
    int e = rfl(es.x), sr = rfl(es.y);
    const float* __restrict__ efp = &ef[(size_t)e * 32];
    float qx = clx, qy = cly;
#pragma unroll
    for (int u = 0; u < 8; ++u) {
      float4 v = *(const float4*)&efp[4 * u];
      qx = fmaf(v.x, Bc[4 * u + 0].x, qx); qy = fmaf(v.x, Bc[4 * u + 0].y, qy);
      qx = fmaf(v.y, Bc[4 * u + 1].x, qx); qy = fmaf(v.y, Bc[4 * u + 1].y, qy);
      qx = fmaf(v.z, Bc[4 * u + 2].x, qx); qy = fmaf(v.z, Bc[4 * u + 2].y, qy);
      qx = fmaf(v.w, Bc[4 * u + 3].x, qx); qy = fmaf(v.w, Bc[4 * u + 3].y, qy);
    }
    float2 p2 = *(const float2*)&PRA[(size_t)sr * 64 + 2 * l5];
    float rx = fmaxf(qx + p2.x, 0.f), ry = fmaxf(qy + p2.y, 0.f);
    if (half == 0) { accx += rx; accy += ry; }
  }

  // combine halves and store
  accx += __shfl_xor(accx, 32);
  accy += __shfl_xor(accy, 32);
  if (half == 0)
    *(float2*)&H[(size_t)n * 64 + 2 * l5] = make_float2(accx, accy);
}

// ---------------------------------------------------------------------------
// Final per-node MLP with W2U fold:
//   pre = PRU[n] + H[n]@W2U + deg*d2 + bu1 ; out = relu(pre)@wu2 + bu2
// ---------------------------------------------------------------------------
__global__ __launch_bounds__(256) void k_update3(
    const float* __restrict__ H, const int* __restrict__ strt,
    const float* __restrict__ PRU,
    const float* __restrict__ W2U, const float* __restrict__ d2,
    const float* __restrict__ bu1,
    const float* __restrict__ wu2, const float* __restrict__ bu2,
    float* __restrict__ out) {
  int n = blockIdx.x * 256 + threadIdx.x;
  if (n >= NN) return;

  float Hr[64];
#pragma unroll
  for (int k = 0; k < 64; k += 4)
    *(float4*)&Hr[k] = *(const float4*)&H[(size_t)n * 64 + k];
  float deg = (float)(strt[n + 1] - strt[n]);

  float acc[64];
#pragma unroll
  for (int o = 0; o < 64; ++o) acc[o] = bu2[o];

  const float* __restrict__ prs = &PRU[(size_t)n * 64];
#pragma unroll 1
  for (int jc = 0; jc < 64; jc += 16) {
    float q[16];
#pragma unroll
    for (int jj = 0; jj < 16; ++jj) q[jj] = bu1[jc + jj] + deg * d2[jc + jj];
#pragma unroll
    for (int k = 0; k < 64; ++k) {
      float hv = Hr[k];
#pragma unroll
      for (int jj = 0; jj < 16; ++jj) q[jj] += hv * W2U[k * 64 + jc + jj];
    }
#pragma unroll
    for (int jj = 0; jj < 16; ++jj) {
      float h = fmaxf(prs[jc + jj] + q[jj], 0.f);
#pragma unroll
      for (int o = 0; o < 64; ++o) acc[o] += h * wu2[(jc + jj) * 64 + o];
    }
  }

#pragma unroll
  for (int o = 0; o < 64; o += 4)
    *(float4*)&out[(size_t)n * 64 + o] = make_float4(acc[o], acc[o + 1], acc[o + 2], acc[o + 3]);
}

// ---------------------------------------------------------------------------
// Fallback (ws too small): round-1 atomic scatter path
// ---------------------------------------------------------------------------
__global__ __launch_bounds__(256) void k_edge_at(
    const int* __restrict__ idx, const float* __restrict__ ef,
    const float* __restrict__ B, const float* __restrict__ c,
    const float* __restrict__ wm2, const float* __restrict__ bm2,
    const float* __restrict__ PRA, float* __restrict__ agg) {
  int e = blockIdx.x * 256 + threadIdx.x;
  if (e >= NE) return;
  int src = idx[e];
  int dst = idx[NE + e];
  float efr[32];
#pragma unroll
  for (int k = 0; k < 32; k += 4)
    *(float4*)&efr[k] = *(const float4*)&ef[(size_t)e * 32 + k];
  float m[64];
#pragma unroll
  for (int o = 0; o < 64; ++o) m[o] = bm2[o];
  const float* __restrict__ prs = &PRA[(size_t)src * 64];
#pragma unroll 1
  for (int jc = 0; jc < 64; jc += 16) {
    float q[16];
#pragma unroll
    for (int jj = 0; jj < 16; ++jj) q[jj] = c[jc + jj];
#pragma unroll
    for (int k = 0; k < 32; ++k) {
      float ev = efr[k];
#pragma unroll
      for (int jj = 0; jj < 16; ++jj) q[jj] += ev * B[k * 64 + jc + jj];
    }
#pragma unroll
    for (int jj = 0; jj < 16; ++jj) {
      float h = fmaxf(prs[jc + jj] + q[jj], 0.f);
#pragma unroll
      for (int o = 0; o < 64; ++o) m[o] += h * wm2[(jc + jj) * 64 + o];
    }
  }
  float* __restrict__ ap = &agg[(size_t)dst * 64];
#pragma unroll
  for (int o = 0; o < 64; ++o) atomicAdd(&ap[o], m[o]);
}

__global__ __launch_bounds__(256) void k_update_at(
    const float* __restrict__ agg, const float* __restrict__ PRU,
    const float* __restrict__ wu1, const float* __restrict__ bu1,
    const float* __restrict__ wu2, const float* __restrict__ bu2,
    float* __restrict__ out) {
  int n = blockIdx.x * 256 + threadIdx.x;
  if (n >= NN) return;
  float ar[64];
#pragma unroll
  for (int k = 0; k < 64; k += 4)
    *(float4*)&ar[k] = *(const float4*)&agg[(size_t)n * 64 + k];
  float acc[64];
#pragma unroll
  for (int o = 0; o < 64; ++o) acc[o] = bu2[o];
  const float* __restrict__ prs = &PRU[(size_t)n * 64];
#pragma unroll 1
  for (int jc = 0; jc < 64; jc += 16) {
    float q[16];
#pragma unroll
    for (int jj = 0; jj < 16; ++jj) q[jj] = bu1[jc + jj];
#pragma unroll
    for (int k = 0; k < 64; ++k) {
      float av = ar[k];
#pragma unroll
      for (int jj = 0; jj < 16; ++jj) q[jj] += av * wu1[(128 + k) * 64 + jc + jj];
    }
#pragma unroll
    for (int jj = 0; jj < 16; ++jj) {
      float h = fmaxf(prs[jc + jj] + q[jj], 0.f);
#pragma unroll
      for (int o = 0; o < 64; ++o) acc[o] += h * wu2[(jc + jj) * 64 + o];
    }
  }
#pragma unroll
  for (int o = 0; o < 64; o += 4)
    *(float4*)&out[(size_t)n * 64 + o] = make_float4(acc[o], acc[o + 1], acc[o + 2], acc[o + 3]);
}

extern "C" void kernel_launch(void* const* d_in, const int* in_sizes, int n_in,
                              void* d_out, int out_size, void* d_ws, size_t ws_size,
                              hipStream_t stream) {
  const float* nf  = (const float*)d_in[0];
  const int*   idx = (const int*)d_in[1];
  const float* ef  = (const float*)d_in[2];
  const float* wn  = (const float*)d_in[3];
  const float* bn  = (const float*)d_in[4];
  const float* we  = (const float*)d_in[5];
  const float* be  = (const float*)d_in[6];
  const float* wm1 = (const float*)d_in[7];
  const float* bm1 = (const float*)d_in[8];
  const float* wm2 = (const float*)d_in[9];
  const float* bm2 = (const float*)d_in[10];
  const float* wu1 = (const float*)d_in[11];
  const float* bu1 = (const float*)d_in[12];
  const float* wu2 = (const float*)d_in[13];
  const float* bu2 = (const float*)d_in[14];
  float* out = (float*)d_out;

  float* ws   = (float*)d_ws;
  float* M    = ws + OFF_M;
  float* B    = ws + OFF_B;
  float* c    = ws + OFF_C;
  float* W2U  = ws + OFF_W2U;
  float* d2   = ws + OFF_D2;
  int*   bsum = (int*)(ws + OFF_BSUM);
  int*   boff = (int*)(ws + OFF_BOFF);
  float* PRA  = ws + OFF_PRA;
  float* PRU  = ws + OFF_PRU;
  float* H    = ws + OFF_H;
  int*   hist = (int*)(ws + OFF_HIST);
  int*   cur  = (int*)(ws + OFF_CUR);
  int*   strt = (int*)(ws + OFF_STRT);
  int2*  esrc = (int2*)(ws + OFF_ESRC);

  const int SCAN_BLOCKS = (NN + 1023) / 1024;  // 98

  k_fold<<<(16384 + 2048 + 64 + 4096 + 64 + 255) / 256, 256, 0, stream>>>(
      wn, bn, we, be, wm1, bm1, wm2, bm2, wu1, M, B, c, W2U, d2);
  k_node<<<(NN + 255) / 256, 256, 0, stream>>>(nf, M, PRA, PRU);

  if (ws_size >= (size_t)WS_UNITS * 4) {
    hipMemsetAsync(hist, 0, (size_t)2 * NN * sizeof(int), stream);
    k_hist<<<(NE + 255) / 256, 256, 0, stream>>>(idx, hist);
    k_scanA<<<SCAN_BLOCKS, 1024, 0, stream>>>(hist, strt, bsum);
    k_scanB<<<1, 128, 0, stream>>>(bsum, boff, strt, SCAN_BLOCKS);
    k_scanC<<<SCAN_BLOCKS, 1024, 0, stream>>>(strt, boff);
    k_scatter_pairs2<<<(NE + 255) / 256, 256, 0, stream>>>(idx, strt, cur, esrc);
    k_gather4<<<(NN + 3) / 4, 256, 0, stream>>>(esrc, strt, ef, B, c, PRA, H);
    k_update3<<<(NN + 255) / 256, 256, 0, stream>>>(
        H, strt, PRU, W2U, d2, bu1, wu2, bu2, out);
  } else {
    hipMemsetAsync(H, 0, (size_t)NN * 64 * sizeof(float), stream);
    k_edge_at<<<(NE + 255) / 256, 256, 0, stream>>>(idx, ef, B, c, wm2, bm2, PRA, H);
    k_update_at<<<(NN + 255) / 256, 256, 0, stream>>>(
        H, PRU, wu1, bu1, wu2, bu2, out);
  }
}